// Round 11
// baseline (32.709 us; speedup 1.0000x reference)
//
#include <hip/hip_runtime.h>
#include <hip/hip_bf16.h>
#include <stdint.h>

#define DEV __device__ __forceinline__

typedef short s4v __attribute__((ext_vector_type(4)));   // 4 bf16 (bit pattern)
typedef float f4v __attribute__((ext_vector_type(4)));

static constexpr int T = 4096;
static constexpr int BATCH = 4;
static constexpr int MD = 64;
static constexpr int H = 16;
static constexpr int PB = T * H;        // 65536 permuted elements per batch

// ---------------- mfma 16x16x16 bf16 (D = A[16x16k] * B[16kx16] + C) -------
#if __has_builtin(__builtin_amdgcn_mfma_f32_16x16x16bf16_1k)
DEV f4v mfma16(s4v a, s4v b, f4v c) {
    return __builtin_amdgcn_mfma_f32_16x16x16bf16_1k(a, b, c, 0, 0, 0);
}
#elif __has_builtin(__builtin_amdgcn_mfma_f32_16x16x16_bf16)
typedef __bf16 bf4v __attribute__((ext_vector_type(4)));
DEV f4v mfma16(s4v a, s4v b, f4v c) {
    return __builtin_amdgcn_mfma_f32_16x16x16_bf16(__builtin_bit_cast(bf4v, a),
                                                   __builtin_bit_cast(bf4v, b), c, 0, 0, 0);
}
#else
DEV f4v mfma16(s4v a, s4v b, f4v c) {
    asm("v_mfma_f32_16x16x16_bf16 %0, %1, %2, %0" : "+v"(c) : "v"(a), "v"(b));
    return c;
}
#endif

DEV short f2bf(float x) {               // fp32 -> bf16 RNE (proven; FROZEN —
    uint32_t u = __builtin_bit_cast(uint32_t, x);   // every non-RNE pack
    u += 0x7fffu + ((u >> 16) & 1u);                // variant failed: r2/r7/r10)
    return (short)(u >> 16);
}

DEV s4v pack4(f4v p) {
    return s4v{f2bf(p.x), f2bf(p.y), f2bf(p.z), f2bf(p.w)};
}

DEV float ex2(float x) {
#if __has_builtin(__builtin_amdgcn_exp2f)
    return __builtin_amdgcn_exp2f(x);
#else
    return exp2f(x);
#endif
}

// ---------------------------------------------------------------------------
// K1: QKV projection -> permuted bf16 layout. Q is pre-scaled by 0.25*log2(e)
// so the attention kernel applies exp2 directly to the MFMA output.
// Q/K perm: elem(b,t,h) = b*PB + (t>>4)*256 + (h>>2)*64 + (t&15)*4 + (h&3)
// V   perm: elem(b,t,h) = b*PB + (t>>4)*256 + ((t&15)>>2)*64 + h*4 + (t&3)
// ---------------------------------------------------------------------------
__global__ __launch_bounds__(256) void k_proj(
    const float* __restrict__ idx,
    const float* __restrict__ Wk, const float* __restrict__ bk,
    const float* __restrict__ Wq, const float* __restrict__ bq,
    const float* __restrict__ Wv, const float* __restrict__ bv,
    short* __restrict__ qp, short* __restrict__ kp, short* __restrict__ vp)
{
    const int w = threadIdx.x >> 6, lane = threadIdx.x & 63;
    const int a = lane & 15, g = lane >> 4;
    const int tile = blockIdx.x * 4 + w;        // 0..1023
    const int b = tile >> 8;
    const int trow0 = (tile & 255) << 4;

    const float* rb = idx + (size_t)(b * T + trow0) * MD;

    s4v xf[4], wqf[4], wkf[4], wvf[4];
#pragma unroll
    for (int kc = 0; kc < 4; ++kc) {
        const int ko = kc * 16 + 4 * g;
        f4v x = *(const f4v*)(rb + a * MD + ko);     // idx[t0+a][ko..ko+3]
        f4v q = *(const f4v*)(Wq + a * MD + ko);     // Wq[a][ko..]
        f4v k = *(const f4v*)(Wk + a * MD + ko);
        f4v v = *(const f4v*)(Wv + a * MD + ko);
        xf[kc]  = pack4(x);
        wqf[kc] = pack4(q);
        wkf[kc] = pack4(k);
        wvf[kc] = pack4(v);
    }
    f4v aq = {0.f,0.f,0.f,0.f}, ak = {0.f,0.f,0.f,0.f}, av = {0.f,0.f,0.f,0.f};
#pragma unroll
    for (int kc = 0; kc < 4; ++kc) {
        aq = mfma16(wqf[kc], xf[kc], aq);   // D^T[h][t]: lane t=t0+a, h=4g+r
        ak = mfma16(wkf[kc], xf[kc], ak);
        av = mfma16(xf[kc], wvf[kc], av);   // D[t][h]: lane h=a, t=t0+4g+r
    }
    const int slot = b * PB + (tile & 255) * 256 + g * 64 + a * 4;
    f4v bqv = *(const f4v*)(bq + 4 * g);
    f4v bkv = *(const f4v*)(bk + 4 * g);
    const float bvs = bv[a];
    const float CS = 0.36067376022224085f;      // 0.25 * log2(e), folded into Q
    f4v qv = {(aq.x + bqv.x) * CS, (aq.y + bqv.y) * CS,
              (aq.z + bqv.z) * CS, (aq.w + bqv.w) * CS};
    f4v kv = {ak.x + bkv.x, ak.y + bkv.y, ak.z + bkv.z, ak.w + bkv.w};
    f4v vv = {av.x + bvs, av.y + bvs, av.z + bvs, av.w + bvs};
    *(s4v*)(qp + slot) = pack4(qv);
    *(s4v*)(kp + slot) = pack4(kv);
    *(s4v*)(vp + slot) = pack4(vv);
}

// ---------------------------------------------------------------------------
// Fast (mask-free) run over physical s-tiles [lo, hi).
// DUAL: each K/V load feeds BOTH q-tiles (A and B). Ping-pong groups of 8.
// Tail group: loads clamped to hi-1, compute guarded by st+u < hi.
// ---------------------------------------------------------------------------
template<bool DUAL>
DEV void run_fast(int lo, int hi, s4v QfA, s4v QfB,
                  const short* __restrict__ kb, const short* __restrict__ vb,
                  f4v& accA, float& lpA, f4v& accB, float& lpB)
{
    if (lo >= hi) return;
    const int ng = (hi - lo + 7) >> 3;
    s4v KA[8], VA[8], KB[8], VB[8];

    auto LOADG = [&](s4v* K, s4v* V, int gi) {
        const int st = lo + gi * 8;
#pragma unroll
        for (int u = 0; u < 8; ++u) {
            const int idx = min(st + u, hi - 1);      // clamp tail padding
            K[u] = *(const s4v*)(kb + idx * 256);
            V[u] = *(const s4v*)(vb + idx * 256);
        }
    };
    auto BODY = [&](s4v K, s4v V) {
        if constexpr (DUAL) {
            f4v SA = mfma16(K, QfA, f4v{0.f,0.f,0.f,0.f});
            f4v pa;
#pragma unroll
            for (int r = 0; r < 4; ++r) pa[r] = ex2(SA[r]);
            lpA += pa.x + pa.y + pa.z + pa.w;
            accA = mfma16(pack4(pa), V, accA);
        }
        f4v SB = mfma16(K, QfB, f4v{0.f,0.f,0.f,0.f});
        f4v pb;
#pragma unroll
        for (int r = 0; r < 4; ++r) pb[r] = ex2(SB[r]);
        lpB += pb.x + pb.y + pb.z + pb.w;
        accB = mfma16(pack4(pb), V, accB);
    };
    auto COMPG = [&](const s4v* K, const s4v* V, int gi) {
        const int st = lo + gi * 8;
        if (gi == ng - 1) {                 // tail group: guarded
#pragma unroll
            for (int u = 0; u < 8; ++u)
                if (st + u < hi) BODY(K[u], V[u]);
        } else {
#pragma unroll
            for (int u = 0; u < 8; ++u) BODY(K[u], V[u]);
        }
    };

    int it = 0;
    LOADG(KA, VA, 0);
    for (; it + 2 <= ng; it += 2) {
        LOADG(KB, VB, it + 1);
        COMPG(KA, VA, it);
        if (it + 2 < ng) LOADG(KA, VA, it + 2);
        COMPG(KB, VB, it + 1);
    }
    if (it < ng) COMPG(KA, VA, it);
}

// single tile st: side-1 (Qf1) causally masked vs tq1; optional plain side-2
DEV void tile_masked(int st, int g, s4v Qf1, int tq1,
                     const short* __restrict__ kb, const short* __restrict__ vb,
                     f4v& acc1, float& lp1,
                     bool dual, s4v Qf2, f4v& acc2, float& lp2)
{
    const s4v K = *(const s4v*)(kb + st * 256);
    const s4v V = *(const s4v*)(vb + st * 256);
    const int sb = st * 16 + 4 * g;
    {
        f4v S = mfma16(K, Qf1, f4v{0.f,0.f,0.f,0.f});
        f4v p;
#pragma unroll
        for (int r = 0; r < 4; ++r) {
            const float e = ex2(S[r]);
            p[r] = (sb + r <= tq1) ? e : 0.f;
        }
        lp1 += p.x + p.y + p.z + p.w;
        acc1 = mfma16(pack4(p), V, acc1);
    }
    if (dual) {
        f4v S = mfma16(K, Qf2, f4v{0.f,0.f,0.f,0.f});
        f4v p;
#pragma unroll
        for (int r = 0; r < 4; ++r) p[r] = ex2(S[r]);
        lp2 += p.x + p.y + p.z + p.w;
        acc2 = mfma16(pack4(p), V, acc2);
    }
}

// ---------------------------------------------------------------------------
// K2 (fused): attention + block-local combine + output projection.
// Grid 512 = (b:4) x (pair j:128), 512 threads = 8 waves.
// Round 11: shared-K/V dual-Q walk. Physical tiles [0, 256-j); t <= j feeds
// BOTH q-tiles (A=j, B=255-j) off one load (overlap region was read twice
// before: 257 tile-reads -> 256-j, avg -25%). Work units: dual tile = 2,
// single = 1; total = 257; wave cuts inverted analytically (+-1 unit).
// Masked tiles (A diag t=j, B diag t=255-j) handled outside the fast loops.
// ---------------------------------------------------------------------------
__global__ __launch_bounds__(512, 4) void k_fused(
    const short* __restrict__ qp, const short* __restrict__ kp,
    const short* __restrict__ vp,
    const float* __restrict__ Wp, const float* __restrict__ bp,
    float* __restrict__ out)
{
    const int bx = blockIdx.x;
    const int b = bx >> 7, j = bx & 127;
    const int tid = threadIdx.x;
    const int w = tid >> 6, lane = tid & 63;
    const int a = lane & 15, g = lane >> 4;

    const int qtA = j, qtB = 255 - j;
    const int ntA = j + 1;               // dual tiles: [0, ntA)
    const int NP  = 256 - j;             // physical tiles: [0, NP)

    const short* qb = qp + b * PB;
    const short* kb = kp + b * PB + g * 64 + a * 4;
    const short* vb = vp + b * PB + g * 64 + a * 4;

    const s4v QfA = *(const s4v*)(qb + qtA * 256 + g * 64 + a * 4);
    const s4v QfB = *(const s4v*)(qb + qtB * 256 + g * 64 + a * 4);
    const int tqA = qtA * 16 + a, tqB = qtB * 16 + a;

    // work->tile cut: cum work(t) = 2t (t<=ntA) else ntA+t ; invert at 257w/8
    auto cut = [&](int ww) -> int {
        const int c = (257 * ww) >> 3;
        return (c < 2 * ntA) ? ((c + 1) >> 1) : (c - ntA);
    };
    const int t0 = cut(w), t1 = cut(w + 1);

    f4v accA = {0.f,0.f,0.f,0.f}, accB = {0.f,0.f,0.f,0.f};
    float lpA = 0.f, lpB = 0.f;

    // dual segment [t0, dEnd): fast part excludes A's diagonal tile t=j
    const int dEnd = min(t1, ntA);
    run_fast<true>(t0, min(dEnd, j), QfA, QfB, kb, vb, accA, lpA, accB, lpB);
    if (dEnd == ntA && t0 <= j)          // this wave owns tile j: A masked, B plain
        tile_masked(j, g, QfA, tqA, kb, vb, accA, lpA, true, QfB, accB, lpB);

    // B-only segment [bLo, t1): fast part excludes B's diagonal tile NP-1
    const int bLo = max(t0, ntA);
    run_fast<false>(bLo, (t1 == NP) ? (NP - 1) : t1,
                    QfA, QfB, kb, vb, accA, lpA, accB, lpB);
    if (t1 == NP && bLo <= NP - 1)       // this wave owns B's diagonal
        tile_masked(NP - 1, g, QfB, tqB, kb, vb, accB, lpB,
                    false, QfB, accB, lpB);

    __shared__ float pacc[16 * 64 * 4];  // [(w*2+X)*64 + lane][r]
    __shared__ float plp[16 * 16];       // [(w*2+X)*16 + row]

    *(f4v*)&pacc[((w * 2 + 0) * 64 + lane) * 4] = accA;
    *(f4v*)&pacc[((w * 2 + 1) * 64 + lane) * 4] = accB;

    float lA = lpA + __shfl_xor(lpA, 16); lA += __shfl_xor(lA, 32);
    float lB = lpB + __shfl_xor(lpB, 16); lB += __shfl_xor(lB, 32);
    if (lane < 16) {
        plp[(w * 2 + 0) * 16 + lane] = lA;
        plp[(w * 2 + 1) * 16 + lane] = lB;
    }
    __syncthreads();

    // combine + normalize + output projection: 128 tasks = (X:2, row:16, dc:4)
    if (tid < 128) {
        const int X = tid >> 6, i = (tid >> 2) & 15, dc = tid & 3;
        float av[16];
#pragma unroll
        for (int h = 0; h < 16; ++h) av[h] = 0.f;
        float l = 0.f;
#pragma unroll
        for (int ww = 0; ww < 8; ++ww) {     // fixed wave order: deterministic
            const int base = ((ww * 2 + X) * 64 + (i >> 2) * 16) * 4 + (i & 3);
#pragma unroll
            for (int h = 0; h < 16; ++h) av[h] += pacc[base + h * 4];
            l += plp[(ww * 2 + X) * 16 + i];
        }
        const float inv = 1.f / l;
        const int qt = X ? qtB : qtA;

        float* orow = out + ((size_t)(b * T) + qt * 16 + i) * 64 + dc * 16;
#pragma unroll
        for (int j4 = 0; j4 < 4; ++j4) {
            f4v o;
#pragma unroll
            for (int jj = 0; jj < 4; ++jj) {
                const int d = dc * 16 + j4 * 4 + jj;
                const float* wr = Wp + d * 16;
                float s = 0.f;
#pragma unroll
                for (int h = 0; h < 16; ++h) s += av[h] * wr[h];
                o[jj] = bp[d] + s * inv;
            }
            *(f4v*)(orow + j4 * 4) = o;
        }
    }
}

// ---------------------------------------------------------------------------
// ws layout (bytes): qp 512K | kp 512K | vp 512K   (1.5 MB)
// ---------------------------------------------------------------------------
extern "C" void kernel_launch(void* const* d_in, const int* in_sizes, int n_in,
                              void* d_out, int out_size, void* d_ws, size_t ws_size,
                              hipStream_t stream) {
    const float* idx = (const float*)d_in[0];
    const float* Wk  = (const float*)d_in[1];
    const float* bk  = (const float*)d_in[2];
    const float* Wq  = (const float*)d_in[3];
    const float* bq  = (const float*)d_in[4];
    const float* Wv  = (const float*)d_in[5];
    const float* bv  = (const float*)d_in[6];
    const float* Wp  = (const float*)d_in[7];
    const float* bp  = (const float*)d_in[8];
    float* out = (float*)d_out;

    short* qp = (short*)d_ws;
    short* kp = qp + BATCH * PB;
    short* vp = kp + BATCH * PB;

    k_proj<<<256, 256, 0, stream>>>(idx, Wk, bk, Wq, bq, Wv, bv, qp, kp, vp);
    k_fused<<<512, 512, 0, stream>>>(qp, kp, vp, Wp, bp, out);
}

// Round 12
// 29.807 us; speedup vs baseline: 1.0973x; 1.0973x over previous
//
#include <hip/hip_runtime.h>
#include <hip/hip_bf16.h>
#include <stdint.h>

#define DEV __device__ __forceinline__

typedef short s4v __attribute__((ext_vector_type(4)));   // 4 bf16 (bit pattern)
typedef float f4v __attribute__((ext_vector_type(4)));

static constexpr int T = 4096;
static constexpr int BATCH = 4;
static constexpr int MD = 64;
static constexpr int H = 16;
static constexpr int PB = T * H;        // 65536 permuted elements per batch

// ---------------- mfma 16x16x16 bf16 (D = A[16x16k] * B[16kx16] + C) -------
#if __has_builtin(__builtin_amdgcn_mfma_f32_16x16x16bf16_1k)
DEV f4v mfma16(s4v a, s4v b, f4v c) {
    return __builtin_amdgcn_mfma_f32_16x16x16bf16_1k(a, b, c, 0, 0, 0);
}
#elif __has_builtin(__builtin_amdgcn_mfma_f32_16x16x16_bf16)
typedef __bf16 bf4v __attribute__((ext_vector_type(4)));
DEV f4v mfma16(s4v a, s4v b, f4v c) {
    return __builtin_amdgcn_mfma_f32_16x16x16_bf16(__builtin_bit_cast(bf4v, a),
                                                   __builtin_bit_cast(bf4v, b), c, 0, 0, 0);
}
#else
DEV f4v mfma16(s4v a, s4v b, f4v c) {
    asm("v_mfma_f32_16x16x16_bf16 %0, %1, %2, %0" : "+v"(c) : "v"(a), "v"(b));
    return c;
}
#endif

DEV short f2bf(float x) {               // fp32 -> bf16 RNE (proven; FROZEN —
    uint32_t u = __builtin_bit_cast(uint32_t, x);   // every non-RNE pack
    u += 0x7fffu + ((u >> 16) & 1u);                // variant failed: r2/r7/r10)
    return (short)(u >> 16);
}

DEV s4v pack4(f4v p) {
    return s4v{f2bf(p.x), f2bf(p.y), f2bf(p.z), f2bf(p.w)};
}

DEV float ex2(float x) {
#if __has_builtin(__builtin_amdgcn_exp2f)
    return __builtin_amdgcn_exp2f(x);
#else
    return exp2f(x);
#endif
}

static constexpr short BF1 = 0x3F80;    // bf16 1.0
#define ONES4 (s4v{BF1, BF1, BF1, BF1})

// ---------------------------------------------------------------------------
// K1: QKV projection -> permuted bf16 layout. Q is pre-scaled by 0.25*log2(e)
// so the attention kernel applies exp2 directly to the MFMA output.
// Q/K perm: elem(b,t,h) = b*PB + (t>>4)*256 + (h>>2)*64 + (t&15)*4 + (h&3)
// V   perm: elem(b,t,h) = b*PB + (t>>4)*256 + ((t&15)>>2)*64 + h*4 + (t&3)
// ---------------------------------------------------------------------------
__global__ __launch_bounds__(256) void k_proj(
    const float* __restrict__ idx,
    const float* __restrict__ Wk, const float* __restrict__ bk,
    const float* __restrict__ Wq, const float* __restrict__ bq,
    const float* __restrict__ Wv, const float* __restrict__ bv,
    short* __restrict__ qp, short* __restrict__ kp, short* __restrict__ vp)
{
    const int w = threadIdx.x >> 6, lane = threadIdx.x & 63;
    const int a = lane & 15, g = lane >> 4;
    const int tile = blockIdx.x * 4 + w;        // 0..1023
    const int b = tile >> 8;
    const int trow0 = (tile & 255) << 4;

    const float* rb = idx + (size_t)(b * T + trow0) * MD;

    s4v xf[4], wqf[4], wkf[4], wvf[4];
#pragma unroll
    for (int kc = 0; kc < 4; ++kc) {
        const int ko = kc * 16 + 4 * g;
        f4v x = *(const f4v*)(rb + a * MD + ko);     // idx[t0+a][ko..ko+3]
        f4v q = *(const f4v*)(Wq + a * MD + ko);     // Wq[a][ko..]
        f4v k = *(const f4v*)(Wk + a * MD + ko);
        f4v v = *(const f4v*)(Wv + a * MD + ko);
        xf[kc]  = pack4(x);
        wqf[kc] = pack4(q);
        wkf[kc] = pack4(k);
        wvf[kc] = pack4(v);
    }
    f4v aq = {0.f,0.f,0.f,0.f}, ak = {0.f,0.f,0.f,0.f}, av = {0.f,0.f,0.f,0.f};
#pragma unroll
    for (int kc = 0; kc < 4; ++kc) {
        aq = mfma16(wqf[kc], xf[kc], aq);   // D^T[h][t]: lane t=t0+a, h=4g+r
        ak = mfma16(wkf[kc], xf[kc], ak);
        av = mfma16(xf[kc], wvf[kc], av);   // D[t][h]: lane h=a, t=t0+4g+r
    }
    const int slot = b * PB + (tile & 255) * 256 + g * 64 + a * 4;
    f4v bqv = *(const f4v*)(bq + 4 * g);
    f4v bkv = *(const f4v*)(bk + 4 * g);
    const float bvs = bv[a];
    const float CS = 0.36067376022224085f;      // 0.25 * log2(e), folded into Q
    f4v qv = {(aq.x + bqv.x) * CS, (aq.y + bqv.y) * CS,
              (aq.z + bqv.z) * CS, (aq.w + bqv.w) * CS};
    f4v kv = {ak.x + bkv.x, ak.y + bkv.y, ak.z + bkv.z, ak.w + bkv.w};
    f4v vv = {av.x + bvs, av.y + bvs, av.z + bvs, av.w + bvs};
    *(s4v*)(qp + slot) = pack4(qv);
    *(s4v*)(kp + slot) = pack4(kv);
    *(s4v*)(vp + slot) = pack4(vv);
}

// ---------------------------------------------------------------------------
// Attention over s-tiles [lo, hi) for one Q fragment (round-9 structure).
// 8-tile groups, ping-pong prefetch. Full groups load UNCLAMPED via base
// pointer + compile-time offsets (bit-exact: st+7 < hi for non-tail groups);
// only the tail group clamps + guards + causal-masks.
// lp is accumulated on the MATRIX pipe: accL = mfma(Pf, ONES) ->
// accL[r] = running sum_s P[q=4g+r][s], replicated across lanes a.
// ---------------------------------------------------------------------------
DEV void proc_range(int lo, int hi, s4v Qf, int tq, int g,
                    const short* __restrict__ kb, const short* __restrict__ vb,
                    f4v& acc, f4v& accL)
{
    if (lo >= hi) return;
    const int ng = (hi - lo + 7) >> 3;
    s4v KA[8], VA[8], KB[8], VB[8];

    auto LOADG = [&](s4v* K, s4v* V, int gi) {
        const int st = lo + gi * 8;
        if (gi == ng - 1) {                 // tail: clamp padding
#pragma unroll
            for (int u = 0; u < 8; ++u) {
                const int idx = min(st + u, hi - 1);
                K[u] = *(const s4v*)(kb + idx * 256);
                V[u] = *(const s4v*)(vb + idx * 256);
            }
        } else {                            // full: base + imm offsets
            const short* kpt = kb + st * 256;
            const short* vpt = vb + st * 256;
#pragma unroll
            for (int u = 0; u < 8; ++u) {
                K[u] = *(const s4v*)(kpt + u * 256);
                V[u] = *(const s4v*)(vpt + u * 256);
            }
        }
    };
    auto COMPG = [&](const s4v* K, const s4v* V, int gi) {
        const int st = lo + gi * 8;
        if (gi == ng - 1) {                 // tail group: guarded + masked
#pragma unroll
            for (int u = 0; u < 8; ++u) {
                if (st + u < hi) {
                    f4v S = mfma16(K[u], Qf, f4v{0.f,0.f,0.f,0.f});
                    const int sb = (st + u) * 16 + 4 * g;
                    f4v p;
#pragma unroll
                    for (int r = 0; r < 4; ++r) {
                        const float e = ex2(S[r]);
                        p[r] = (sb + r <= tq) ? e : 0.f;
                    }
                    const s4v Pf = pack4(p);
                    accL = mfma16(Pf, ONES4, accL);
                    acc  = mfma16(Pf, V[u], acc);
                }
            }
        } else {                            // full group: mask-free fast path
#pragma unroll
            for (int u = 0; u < 8; ++u) {
                f4v S = mfma16(K[u], Qf, f4v{0.f,0.f,0.f,0.f});
                f4v p;
#pragma unroll
                for (int r = 0; r < 4; ++r) p[r] = ex2(S[r]);
                const s4v Pf = pack4(p);
                accL = mfma16(Pf, ONES4, accL);
                acc  = mfma16(Pf, V[u], acc);
            }
        }
    };

    int it = 0;
    LOADG(KA, VA, 0);
    for (; it + 2 <= ng; it += 2) {
        LOADG(KB, VB, it + 1);
        COMPG(KA, VA, it);
        if (it + 2 < ng) LOADG(KA, VA, it + 2);
        COMPG(KB, VB, it + 1);
    }
    if (it < ng) COMPG(KA, VA, it);
}

// ---------------------------------------------------------------------------
// K2 (fused): attention + block-local combine + output projection.
// Grid 512 = (b:4) x (pair j:128), 512 threads = 8 waves (4 waves/SIMD at
// 2 blocks/CU). Block owns q-tiles {j, 255-j}: (j+1) + (256-j) = 257 tiles,
// split into 8 balanced slices (257*w)>>3. Partials combined via LDS with
// one __syncthreads (block-local; no device fence, no atomics).
// ---------------------------------------------------------------------------
__global__ __launch_bounds__(512, 4) void k_fused(
    const short* __restrict__ qp, const short* __restrict__ kp,
    const short* __restrict__ vp,
    const float* __restrict__ Wp, const float* __restrict__ bp,
    float* __restrict__ out)
{
    const int bx = blockIdx.x;
    const int b = bx >> 7, j = bx & 127;
    const int tid = threadIdx.x;
    const int w = tid >> 6, lane = tid & 63;
    const int a = lane & 15, g = lane >> 4;

    const int qtA = j, qtB = 255 - j;
    const int ntA = j + 1;               // A s-tiles: [0, ntA)
    const int ntot = 257;                // ntA + (256 - j)

    const short* qb = qp + b * PB;
    const short* kb = kp + b * PB + g * 64 + a * 4;
    const short* vb = vp + b * PB + g * 64 + a * 4;

    const s4v QfA = *(const s4v*)(qb + qtA * 256 + g * 64 + a * 4);
    const s4v QfB = *(const s4v*)(qb + qtB * 256 + g * 64 + a * 4);
    const int tqA = qtA * 16 + a, tqB = qtB * 16 + a;

    // this wave's balanced slice of the virtual tile list
    const int vLo = (ntot * w) >> 3;
    const int vHi = (ntot * (w + 1)) >> 3;

    f4v accA = {0.f,0.f,0.f,0.f}, accB = {0.f,0.f,0.f,0.f};
    f4v accLA = {0.f,0.f,0.f,0.f}, accLB = {0.f,0.f,0.f,0.f};

    // A part: virtual [vLo, min(vHi,ntA)) -> st same range
    proc_range(vLo, min(vHi, ntA), QfA, tqA, g, kb, vb, accA, accLA);
    // B part: virtual [max(vLo,ntA), vHi) -> st = vt - ntA
    proc_range(max(vLo - ntA, 0), vHi - ntA, QfB, tqB, g, kb, vb, accB, accLB);

    __shared__ float pacc[16 * 64 * 4];  // [(w*2+X)*64 + lane][r]
    __shared__ float plp[16 * 16];       // [(w*2+X)*16 + row]

    *(f4v*)&pacc[((w * 2 + 0) * 64 + lane) * 4] = accA;
    *(f4v*)&pacc[((w * 2 + 1) * 64 + lane) * 4] = accB;

    // accL[r] = lp(q-row 4g+r), identical across a -> lanes a==0 write rows
    if (a == 0) {
#pragma unroll
        for (int r = 0; r < 4; ++r) {
            plp[(w * 2 + 0) * 16 + 4 * g + r] = accLA[r];
            plp[(w * 2 + 1) * 16 + 4 * g + r] = accLB[r];
        }
    }
    __syncthreads();

    // combine + normalize + output projection: 128 tasks = (X:2, row:16, dc:4)
    if (tid < 128) {
        const int X = tid >> 6, i = (tid >> 2) & 15, dc = tid & 3;
        float av[16];
#pragma unroll
        for (int h = 0; h < 16; ++h) av[h] = 0.f;
        float l = 0.f;
#pragma unroll
        for (int ww = 0; ww < 8; ++ww) {     // fixed wave order: deterministic
            const int base = ((ww * 2 + X) * 64 + (i >> 2) * 16) * 4 + (i & 3);
#pragma unroll
            for (int h = 0; h < 16; ++h) av[h] += pacc[base + h * 4];
            l += plp[(ww * 2 + X) * 16 + i];
        }
        const float inv = 1.f / l;
        const int qt = X ? qtB : qtA;

        float* orow = out + ((size_t)(b * T) + qt * 16 + i) * 64 + dc * 16;
#pragma unroll
        for (int j4 = 0; j4 < 4; ++j4) {
            f4v o;
#pragma unroll
            for (int jj = 0; jj < 4; ++jj) {
                const int d = dc * 16 + j4 * 4 + jj;
                const float* wr = Wp + d * 16;
                float s = 0.f;
#pragma unroll
                for (int h = 0; h < 16; ++h) s += av[h] * wr[h];
                o[jj] = bp[d] + s * inv;
            }
            *(f4v*)(orow + j4 * 4) = o;
        }
    }
}

// ---------------------------------------------------------------------------
// ws layout (bytes): qp 512K | kp 512K | vp 512K   (1.5 MB)
// ---------------------------------------------------------------------------
extern "C" void kernel_launch(void* const* d_in, const int* in_sizes, int n_in,
                              void* d_out, int out_size, void* d_ws, size_t ws_size,
                              hipStream_t stream) {
    const float* idx = (const float*)d_in[0];
    const float* Wk  = (const float*)d_in[1];
    const float* bk  = (const float*)d_in[2];
    const float* Wq  = (const float*)d_in[3];
    const float* bq  = (const float*)d_in[4];
    const float* Wv  = (const float*)d_in[5];
    const float* bv  = (const float*)d_in[6];
    const float* Wp  = (const float*)d_in[7];
    const float* bp  = (const float*)d_in[8];
    float* out = (float*)d_out;

    short* qp = (short*)d_ws;
    short* kp = qp + BATCH * PB;
    short* vp = kp + BATCH * PB;

    k_proj<<<256, 256, 0, stream>>>(idx, Wk, bk, Wq, bq, Wv, bv, qp, kp, vp);
    k_fused<<<512, 512, 0, stream>>>(qp, kp, vp, Wp, bp, out);
}